// Round 3
// baseline (470.594 us; speedup 1.0000x reference)
//
#include <hip/hip_runtime.h>

#define N_    8
#define C_    256
#define K_    7
#define HID_  10
#define OUTC_ 60
#define S_    16384
#define BN_EPS 1e-5f

// ---- workspace layout (float offsets, all 16B-aligned) ----
#define OFF_NUM    0        // N*C*K = 14336
#define OFF_DEN    14336    // 64
#define OFF_EB     14400    // 64
#define OFF_M2     14464    // N*60*7 = 3360 -> pad 3392
#define OFF_WPT68  17856    // N*256*68 = 139264  (Wp1^T cols 0..59, Wqk cols 60..66, pad 67)
#define OFF_PART   157120   // 512*120 = 61440
#define OFF_SCL    218560   // 64
#define OFF_SHF    218624   // 64
// total 218688 floats = 875 KB

#define GLDS(g, l) __builtin_amdgcn_global_load_lds( \
    (const __attribute__((address_space(1))) unsigned int*)(g), \
    (__attribute__((address_space(3))) unsigned int*)(l), 16, 0, 0)

__device__ __forceinline__ float4 f4max(float4 a, float4 b) {
    return make_float4(fmaxf(a.x,b.x), fmaxf(a.y,b.y), fmaxf(a.z,b.z), fmaxf(a.w,b.w));
}

// ---------------- kernel A: fused class-softmax + pooling GEMM ----------------
// 512 blocks: xcd-chunked so XCD x owns n=x (seg slice becomes L2-resident)
__global__ void __launch_bounds__(256) k_pool(
        const float* __restrict__ fea, const float* __restrict__ seg,
        float* __restrict__ num, float* __restrict__ den) {
    int b = blockIdx.x;
    int lin = (b & 7) * 64 + (b >> 3);
    int n = lin >> 6, r = lin & 63;
    int c0 = (r >> 1) * 8, sh = r & 1;
    int tid = threadIdx.x;
    const float* sp = seg + (size_t)n * K_ * S_ + sh * 8192;
    const float* fp = fea + ((size_t)n * C_ + c0) * S_ + sh * 8192;
    int t4 = tid * 4;

    float acc[8][K_] = {};
    float dsum[K_] = {};
    float4 cf[8], nf[8], cs[K_], ns[K_];
#pragma unroll
    for (int c = 0; c < 8; c++) cf[c] = *(const float4*)(fp + (size_t)c * S_ + t4);
#pragma unroll
    for (int k = 0; k < K_; k++) cs[k] = *(const float4*)(sp + (size_t)k * S_ + t4);

    for (int it = 0; it < 8; it++) {
        int nb = (it + 1) * 1024 + t4;
        if (it < 7) {
#pragma unroll
            for (int c = 0; c < 8; c++) nf[c] = *(const float4*)(fp + (size_t)c * S_ + nb);
#pragma unroll
            for (int k = 0; k < K_; k++) ns[k] = *(const float4*)(sp + (size_t)k * S_ + nb);
        }
        // vectorized class-softmax over 4 px
        float4 m = cs[0];
#pragma unroll
        for (int k = 1; k < K_; k++) m = f4max(m, cs[k]);
        float4 e[K_];
        float4 sum = make_float4(0.f, 0.f, 0.f, 0.f);
#pragma unroll
        for (int k = 0; k < K_; k++) {
            e[k] = make_float4(__expf(cs[k].x - m.x), __expf(cs[k].y - m.y),
                               __expf(cs[k].z - m.z), __expf(cs[k].w - m.w));
            sum.x += e[k].x; sum.y += e[k].y; sum.z += e[k].z; sum.w += e[k].w;
        }
        float4 inv = make_float4(1.f/sum.x, 1.f/sum.y, 1.f/sum.z, 1.f/sum.w);
#pragma unroll
        for (int k = 0; k < K_; k++) {
            float4 a = make_float4(e[k].x*inv.x, e[k].y*inv.y, e[k].z*inv.z, e[k].w*inv.w);
            dsum[k] += a.x + a.y + a.z + a.w;
#pragma unroll
            for (int c = 0; c < 8; c++)
                acc[c][k] += cf[c].x*a.x + cf[c].y*a.y + cf[c].z*a.z + cf[c].w*a.w;
        }
        if (it < 7) {
#pragma unroll
            for (int c = 0; c < 8; c++) cf[c] = nf[c];
#pragma unroll
            for (int k = 0; k < K_; k++) cs[k] = ns[k];
        }
    }
    __shared__ float red[4][63];
    int lane = tid & 63, wv = tid >> 6;
#pragma unroll
    for (int i = 0; i < 56; i++) {
        float v = acc[i / K_][i % K_];
        for (int off = 32; off; off >>= 1) v += __shfl_xor(v, off, 64);
        if (lane == 0) red[wv][i] = v;
    }
    if (c0 == 0) {
#pragma unroll
        for (int k = 0; k < K_; k++) {
            float v = dsum[k];
            for (int off = 32; off; off >>= 1) v += __shfl_xor(v, off, 64);
            if (lane == 0) red[wv][56 + k] = v;
        }
    }
    __syncthreads();
    if (tid < 56) {
        float v = red[0][tid] + red[1][tid] + red[2][tid] + red[3][tid];
        atomicAdd(&num[((size_t)n * C_ + c0 + tid / K_) * K_ + tid % K_], v);
    } else if (tid >= 56 && tid < 63 && c0 == 0) {
        float v = red[0][tid] + red[1][tid] + red[2][tid] + red[3][tid];
        atomicAdd(&den[n * K_ + (tid - 56)], v);
    }
}

// ---------------- kernel B: p_center -> query -> wpt68, ebias, M2 ----------------
__global__ void k_center(const float* __restrict__ num, const float* __restrict__ den,
                         const float* __restrict__ Wq, const float* __restrict__ bq,
                         const float* __restrict__ Wk, const float* __restrict__ bk,
                         const float* __restrict__ Wp,
                         float* __restrict__ eb, float* __restrict__ m2,
                         float* __restrict__ wpt68) {
    int n = blockIdx.x, tid = threadIdx.x;
    __shared__ float pc[C_ * K_];     // [c][k]
    __shared__ float ql[HID_ * K_];   // [o][k]
    __shared__ float dinv[K_];
    if (tid < K_) dinv[tid] = 1.f / den[n * K_ + tid];
    __syncthreads();
    for (int i = tid; i < C_ * K_; i += 256)
        pc[i] = num[(size_t)n * C_ * K_ + i] * dinv[i % K_];
    __syncthreads();
    if (tid < HID_ * K_) {
        int o = tid / K_, k = tid % K_;
        float s = bq[o];
        for (int c = 0; c < C_; c++) s += Wq[o * C_ + c] * pc[c * K_ + k];
        ql[tid] = s;
    }
    __syncthreads();
    // combined weight matrix [c][68]: cols 0..59 = Wp1^T, 60..66 = Wqk, 67 = 0
    for (int i = tid; i < C_ * 68; i += 256) {
        int c = i / 68, o = i % 68;
        float v = 0.f;
        if (o < 60) v = Wp[o * 2 * C_ + c];
        else if (o < 67) {
            int k = o - 60;
            for (int o2 = 0; o2 < HID_; o2++) v += ql[o2 * K_ + k] * Wk[o2 * C_ + c];
        }
        wpt68[(size_t)n * C_ * 68 + i] = v;
    }
    if (tid < K_) {
        float s = 0.f;
        for (int o = 0; o < HID_; o++) s += ql[o * K_ + tid] * bk[o];
        eb[n * K_ + tid] = s;
    }
    for (int i = tid; i < OUTC_ * K_; i += 256) {
        int o = i / K_, k = i % K_;
        float s = 0.f;
        for (int c = 0; c < C_; c++) s += Wp[o * 2 * C_ + C_ + c] * pc[c * K_ + k];
        m2[(size_t)n * OUTC_ * K_ + i] = s;
    }
}

// ---------------- kernel C: fused energy/softmax/projection ----------------
// 512 blocks (xcd-chunked: XCD x owns n=x), 256 px/block, 2-phase LDS pipeline
__global__ void __launch_bounds__(256) k_main(
        const float* __restrict__ fea, const float* __restrict__ wpt68,
        const float* __restrict__ ebias, const float* __restrict__ m2,
        float* __restrict__ y, float* __restrict__ part) {
    int g = blockIdx.x;
    int lin = (g & 7) * 64 + (g >> 3);
    int n = lin >> 6, tile = lin & 63;
    int tid = threadIdx.x;
    int lane = tid & 63, wv = tid >> 6;

    __shared__ __align__(16) float sfe[2][16 * 256];   // 2 x 16KB fea chunk
    __shared__ __align__(16) float swp[2][1088];       // 2 x 4.25KB weight chunk
    __shared__ __align__(16) float sm2[OUTC_ * K_];
    __shared__ float red[4][120];

    if (tid < 105) {
        const float4* src = (const float4*)(m2 + (size_t)n * OUTC_ * K_);
        ((float4*)sm2)[tid] = src[tid];
    }

    const float* fbase = fea + (size_t)n * C_ * S_ + tile * 256;
    const float* wbase = wpt68 + (size_t)n * C_ * 68;

    auto stage = [&](int ch, int bb) {
        const float* fs = fbase + (size_t)ch * 16 * S_;
#pragma unroll
        for (int i = 0; i < 4; i++) {
            int rr = i * 4 + wv;                       // wave-uniform row
            GLDS(fs + (size_t)rr * S_ + lane * 4, &sfe[bb][rr * 256]);
        }
        const float* wsrc = wbase + (size_t)ch * 1088;
        GLDS(wsrc + (wv * 68 + lane) * 4, &swp[bb][wv * 272]);
        if (lane < 4)
            GLDS(wsrc + (wv * 68 + 64 + lane) * 4, &swp[bb][wv * 272 + 256]);
    };

    float ya[68];
#pragma unroll
    for (int i = 0; i < 68; i++) ya[i] = 0.f;

    stage(0, 0);
    asm volatile("s_waitcnt vmcnt(0) lgkmcnt(0)" ::: "memory");
    __builtin_amdgcn_s_barrier();

    for (int ch = 0; ch < 16; ch++) {
        int bb = ch & 1;
        if (ch < 15) stage(ch + 1, bb ^ 1);
#pragma unroll
        for (int c = 0; c < 16; c++) {
            float f = sfe[bb][c * 256 + tid];
            const float4* wrow = (const float4*)&swp[bb][c * 68];
#pragma unroll
            for (int j = 0; j < 17; j++) {
                float4 w = wrow[j];
                ya[j * 4 + 0] += w.x * f;
                ya[j * 4 + 1] += w.y * f;
                ya[j * 4 + 2] += w.z * f;
                ya[j * 4 + 3] += w.w * f;
            }
        }
        asm volatile("s_waitcnt vmcnt(0)" ::: "memory");
        __builtin_amdgcn_s_barrier();
    }

    // softmax over 7 classes + M2 @ attention
    {
        float ek[K_];
#pragma unroll
        for (int k = 0; k < K_; k++) ek[k] = ya[60 + k] + ebias[n * K_ + k];
        float m = ek[0];
#pragma unroll
        for (int k = 1; k < K_; k++) m = fmaxf(m, ek[k]);
        float a[K_]; float sum = 0.f;
#pragma unroll
        for (int k = 0; k < K_; k++) { a[k] = __expf(ek[k] - m); sum += a[k]; }
        float inv = 1.f / sum;
#pragma unroll
        for (int k = 0; k < K_; k++) a[k] *= inv;
#pragma unroll
        for (int o = 0; o < OUTC_; o++) {
            float s = 0.f;
#pragma unroll
            for (int k = 0; k < K_; k++) s += sm2[o * K_ + k] * a[k];
            ya[o] += s;
        }
    }

    // store pre-BN y + BN partial sums
    float* yp = y + (size_t)n * OUTC_ * S_ + tile * 256 + tid;
#pragma unroll
    for (int o = 0; o < OUTC_; o++) {
        float v = ya[o];
        yp[(size_t)o * S_] = v;
        float sm = v, sq = v * v;
        for (int off = 32; off; off >>= 1) {
            sm += __shfl_xor(sm, off, 64);
            sq += __shfl_xor(sq, off, 64);
        }
        if (lane == 0) { red[wv][o] = sm; red[wv][60 + o] = sq; }
    }
    __syncthreads();
    if (tid < 120)
        part[(size_t)blockIdx.x * 120 + tid] =
            red[0][tid] + red[1][tid] + red[2][tid] + red[3][tid];
}

// ---------------- kernel D: BN statistics ----------------
__global__ void k_bn(const float* __restrict__ part, const float* __restrict__ gamma,
                     const float* __restrict__ beta, float* __restrict__ scl,
                     float* __restrict__ shf) {
    int t = threadIdx.x & 127, q = threadIdx.x >> 7;   // 512 threads
    __shared__ float red[4][120];
    __shared__ float tot[120];
    if (t < 120) {
        float s = 0.f;
        for (int b = q * 128; b < q * 128 + 128; b++) s += part[(size_t)b * 120 + t];
        red[q][t] = s;
    }
    __syncthreads();
    if (threadIdx.x < 120)
        tot[threadIdx.x] = red[0][threadIdx.x] + red[1][threadIdx.x] +
                           red[2][threadIdx.x] + red[3][threadIdx.x];
    __syncthreads();
    if (threadIdx.x < OUTC_) {
        const float invn = 1.f / (float)(N_ * S_);
        float mean = tot[threadIdx.x] * invn;
        float var = tot[60 + threadIdx.x] * invn - mean * mean;
        float sc = gamma[threadIdx.x] * rsqrtf(var + BN_EPS);
        scl[threadIdx.x] = sc;
        shf[threadIdx.x] = beta[threadIdx.x] - mean * sc;
    }
}

// ---------------- kernel E: in-place BN apply + ReLU ----------------
__global__ void k_apply(float* __restrict__ y, const float* __restrict__ scl,
                        const float* __restrict__ shf) {
    int idx = blockIdx.x * 256 + threadIdx.x;          // float4 index
    int o = (idx >> 12) % OUTC_;
    float4 v = ((const float4*)y)[idx];
    float a = scl[o], b = shf[o];
    v.x = fmaxf(v.x * a + b, 0.f);
    v.y = fmaxf(v.y * a + b, 0.f);
    v.z = fmaxf(v.z * a + b, 0.f);
    v.w = fmaxf(v.w * a + b, 0.f);
    ((float4*)y)[idx] = v;
}

extern "C" void kernel_launch(void* const* d_in, const int* in_sizes, int n_in,
                              void* d_out, int out_size, void* d_ws, size_t ws_size,
                              hipStream_t stream) {
    const float* p_fea = (const float*)d_in[0];
    const float* p_seg = (const float*)d_in[1];
    const float* Wq    = (const float*)d_in[2];
    const float* bq    = (const float*)d_in[3];
    const float* Wk    = (const float*)d_in[4];
    const float* bk    = (const float*)d_in[5];
    const float* Wp    = (const float*)d_in[6];
    const float* gamma = (const float*)d_in[7];
    const float* beta  = (const float*)d_in[8];

    float* ws    = (float*)d_ws;
    float* num   = ws + OFF_NUM;
    float* den   = ws + OFF_DEN;
    float* eb    = ws + OFF_EB;
    float* m2    = ws + OFF_M2;
    float* wpt68 = ws + OFF_WPT68;
    float* part  = ws + OFF_PART;
    float* scl   = ws + OFF_SCL;
    float* shf   = ws + OFF_SHF;
    float* ybuf  = (float*)d_out;

    hipMemsetAsync(num, 0, 14400 * sizeof(float), stream);   // num + den
    k_pool<<<512, 256, 0, stream>>>(p_fea, p_seg, num, den);
    k_center<<<8, 256, 0, stream>>>(num, den, Wq, bq, Wk, bk, Wp, eb, m2, wpt68);
    k_main<<<512, 256, 0, stream>>>(p_fea, wpt68, eb, m2, ybuf, part);
    k_bn<<<1, 512, 0, stream>>>(part, gamma, beta, scl, shf);
    k_apply<<<(N_ * OUTC_ * S_ / 4) / 256, 256, 0, stream>>>(ybuf, scl, shf);
}

// Round 4
// 202.323 us; speedup vs baseline: 2.3260x; 2.3260x over previous
//
#include <hip/hip_runtime.h>

#define N_    8
#define C_    256
#define K_    7
#define HID_  10
#define OUTC_ 60
#define S_    16384
#define BN_EPS 1e-5f

// ---- workspace layout (float offsets, all 16B-aligned) ----
#define OFF_NUM    0        // N*C*K = 14336
#define OFF_DEN    14336    // 64
#define OFF_EB     14400    // 64
#define OFF_M2     14464    // 3392
#define OFF_WPT80  17856    // N*256*80 = 163840 (col 20w+j = output 17w+j, j<17)
#define OFF_PART   181696   // 512*120 = 61440
#define OFF_SCL    243136   // 64
#define OFF_SHF    243200   // 64
// total 243264 floats = 973 KB

#define GLDS(g, l) __builtin_amdgcn_global_load_lds( \
    (const __attribute__((address_space(1))) unsigned int*)(g), \
    (__attribute__((address_space(3))) unsigned int*)(l), 16, 0, 0)

__device__ __forceinline__ float4 f4max(float4 a, float4 b) {
    return make_float4(fmaxf(a.x,b.x), fmaxf(a.y,b.y), fmaxf(a.z,b.z), fmaxf(a.w,b.w));
}

// ---------------- kernel A: fused class-softmax + pooling GEMM ----------------
// 512 blocks xcd-chunked: XCD x owns n=x
__global__ void __launch_bounds__(256) k_pool(
        const float* __restrict__ fea, const float* __restrict__ seg,
        float* __restrict__ num, float* __restrict__ den) {
    int b = blockIdx.x;
    int lin = (b & 7) * 64 + (b >> 3);
    int n = lin >> 6, r = lin & 63;
    int c0 = (r >> 1) * 8, sh = r & 1;
    int tid = threadIdx.x;
    const float* sp = seg + (size_t)n * K_ * S_ + sh * 8192 + tid * 4;
    const float* fp = fea + ((size_t)n * C_ + c0) * S_ + sh * 8192 + tid * 4;

    float acc[8][K_] = {};
    float dsum[K_] = {};
#pragma unroll 2
    for (int it = 0; it < 8; it++) {
        int s = it * 1024;
        float4 sv[K_], fv[8];
#pragma unroll
        for (int k = 0; k < K_; k++) sv[k] = *(const float4*)(sp + (size_t)k * S_ + s);
#pragma unroll
        for (int c = 0; c < 8; c++) fv[c] = *(const float4*)(fp + (size_t)c * S_ + s);
        float4 m = sv[0];
#pragma unroll
        for (int k = 1; k < K_; k++) m = f4max(m, sv[k]);
        float4 sum = make_float4(0.f, 0.f, 0.f, 0.f);
        float4 a[K_];
#pragma unroll
        for (int k = 0; k < K_; k++) {
            a[k] = make_float4(__expf(sv[k].x - m.x), __expf(sv[k].y - m.y),
                               __expf(sv[k].z - m.z), __expf(sv[k].w - m.w));
            sum.x += a[k].x; sum.y += a[k].y; sum.z += a[k].z; sum.w += a[k].w;
        }
        float4 inv = make_float4(1.f/sum.x, 1.f/sum.y, 1.f/sum.z, 1.f/sum.w);
#pragma unroll
        for (int k = 0; k < K_; k++) {
            a[k] = make_float4(a[k].x*inv.x, a[k].y*inv.y, a[k].z*inv.z, a[k].w*inv.w);
            dsum[k] += a[k].x + a[k].y + a[k].z + a[k].w;
        }
#pragma unroll
        for (int c = 0; c < 8; c++)
#pragma unroll
            for (int k = 0; k < K_; k++)
                acc[c][k] += fv[c].x*a[k].x + fv[c].y*a[k].y + fv[c].z*a[k].z + fv[c].w*a[k].w;
    }
    __shared__ float red[4][63];
    int lane = tid & 63, wv = tid >> 6;
#pragma unroll
    for (int i = 0; i < 56; i++) {
        float v = acc[i / K_][i % K_];
        for (int off = 32; off; off >>= 1) v += __shfl_xor(v, off, 64);
        if (lane == 0) red[wv][i] = v;
    }
    if (c0 == 0) {
#pragma unroll
        for (int k = 0; k < K_; k++) {
            float v = dsum[k];
            for (int off = 32; off; off >>= 1) v += __shfl_xor(v, off, 64);
            if (lane == 0) red[wv][56 + k] = v;
        }
    }
    __syncthreads();
    if (tid < 56) {
        float v = red[0][tid] + red[1][tid] + red[2][tid] + red[3][tid];
        atomicAdd(&num[((size_t)n * C_ + c0 + tid / K_) * K_ + tid % K_], v);
    } else if (tid >= 56 && tid < 63 && c0 == 0) {
        float v = red[0][tid] + red[1][tid] + red[2][tid] + red[3][tid];
        atomicAdd(&den[n * K_ + (tid - 56)], v);
    }
}

// ---------------- kernel B: p_center -> query -> wpt80, ebias, M2 ----------------
__global__ void k_center(const float* __restrict__ num, const float* __restrict__ den,
                         const float* __restrict__ Wq, const float* __restrict__ bq,
                         const float* __restrict__ Wk, const float* __restrict__ bk,
                         const float* __restrict__ Wp,
                         float* __restrict__ eb, float* __restrict__ m2,
                         float* __restrict__ wpt80) {
    int n = blockIdx.x, tid = threadIdx.x;
    __shared__ float pc[C_ * K_];     // [c][k]
    __shared__ float ql[HID_ * K_];   // [o][k]
    __shared__ float dinv[K_];
    if (tid < K_) dinv[tid] = 1.f / den[n * K_ + tid];
    __syncthreads();
    for (int i = tid; i < C_ * K_; i += 256)
        pc[i] = num[(size_t)n * C_ * K_ + i] * dinv[i % K_];
    __syncthreads();
    if (tid < HID_ * K_) {
        int o = tid / K_, k = tid % K_;
        float s = bq[o];
        for (int c = 0; c < C_; c++) s += Wq[o * C_ + c] * pc[c * K_ + k];
        ql[tid] = s;
    }
    __syncthreads();
    // wpt80[c][80]: col 20w+j (j<17) = output o=17w+j; o<60 -> Wp1^T, 60..66 -> Wqk
    for (int i = tid; i < C_ * 80; i += 256) {
        int c = i / 80, cc = i % 80;
        int w = cc / 20, j = cc % 20;
        float v = 0.f;
        if (j < 17) {
            int o = 17 * w + j;
            if (o < 60) v = Wp[o * 2 * C_ + c];
            else if (o < 67) {
                int k = o - 60;
                for (int o2 = 0; o2 < HID_; o2++) v += ql[o2 * K_ + k] * Wk[o2 * C_ + c];
            }
        }
        wpt80[(size_t)n * C_ * 80 + i] = v;
    }
    if (tid < K_) {
        float s = 0.f;
        for (int o = 0; o < HID_; o++) s += ql[o * K_ + tid] * bk[o];
        eb[n * K_ + tid] = s;
    }
    for (int i = tid; i < OUTC_ * K_; i += 256) {
        int o = i / K_, k = i % K_;
        float s = 0.f;
        for (int c = 0; c < C_; c++) s += Wp[o * 2 * C_ + C_ + c] * pc[c * K_ + k];
        m2[(size_t)n * OUTC_ * K_ + i] = s;
    }
}

// ---------------- kernel C: fused energy/softmax/projection ----------------
// 512 blocks xcd-chunked; 4 waves x 17 outputs, 4 px/thread (1024 px/block? no: 256 px)
// wave w owns outputs 17w..17w+16; thread owns px tile*256 + lane*4 .. +3
__global__ void __launch_bounds__(256, 4) k_main(
        const float* __restrict__ fea, const float* __restrict__ wpt80,
        const float* __restrict__ ebias, const float* __restrict__ m2,
        float* __restrict__ y, float* __restrict__ part) {
    int g = blockIdx.x;
    int lin = (g & 7) * 64 + (g >> 3);
    int n = lin >> 6, tile = lin & 63;
    int tid = threadIdx.x, lane = tid & 63, wv = tid >> 6;

    __shared__ __align__(16) float sw[2][5120];      // 2 x 20KB weight chunks
    __shared__ __align__(16) float sm2[424];
    __shared__ __align__(16) float a_lds[K_][256];
    __shared__ float tot[120];

    for (int i = tid; i < OUTC_ * K_; i += 256)
        sm2[i] = m2[(size_t)n * OUTC_ * K_ + i];

    const float* wsrc = wpt80 + (size_t)n * (C_ * 80);
    const float* fp = fea + (size_t)n * C_ * S_ + tile * 256 + lane * 4;

    float4 acc[17];
#pragma unroll
    for (int i = 0; i < 17; i++) acc[i] = make_float4(0.f, 0.f, 0.f, 0.f);

    {   // stage chunk 0
#pragma unroll
        for (int i = 0; i < 5; i++) {
            int fi = i * 1024 + wv * 256;            // wave-uniform lds base
            GLDS(wsrc + fi + lane * 4, &sw[0][fi]);
        }
    }
    asm volatile("s_waitcnt vmcnt(0)" ::: "memory");
    __builtin_amdgcn_s_barrier();

    const int wb = 20 * wv;
    float4 fcur = *(const float4*)fp;
    for (int ch = 0; ch < 4; ch++) {
        int bb = ch & 1;
        if (ch < 3) {
            const float* s1 = wsrc + (ch + 1) * 5120;
#pragma unroll
            for (int i = 0; i < 5; i++) {
                int fi = i * 1024 + wv * 256;
                GLDS(s1 + fi + lane * 4, &sw[bb ^ 1][fi]);
            }
        }
#pragma unroll 4
        for (int cc = 0; cc < 64; cc++) {
            float4 f = fcur;
            int cn = (ch * 64 + cc + 1) & 255;
            fcur = *(const float4*)(fp + (size_t)cn * S_);   // prefetch next c
            const float* wr = &sw[bb][cc * 80 + wb];         // wave-uniform -> broadcast
            float4 w0 = *(const float4*)wr;
            float4 w1 = *(const float4*)(wr + 4);
            float4 w2 = *(const float4*)(wr + 8);
            float4 w3 = *(const float4*)(wr + 12);
            float wx = wr[16];
#define FMA4(j, ww) acc[j].x += (ww) * f.x; acc[j].y += (ww) * f.y; \
                    acc[j].z += (ww) * f.z; acc[j].w += (ww) * f.w;
            FMA4(0, w0.x) FMA4(1, w0.y) FMA4(2, w0.z) FMA4(3, w0.w)
            FMA4(4, w1.x) FMA4(5, w1.y) FMA4(6, w1.z) FMA4(7, w1.w)
            FMA4(8, w2.x) FMA4(9, w2.y) FMA4(10, w2.z) FMA4(11, w2.w)
            FMA4(12, w3.x) FMA4(13, w3.y) FMA4(14, w3.z) FMA4(15, w3.w)
            FMA4(16, wx)
#undef FMA4
        }
        asm volatile("s_waitcnt vmcnt(0)" ::: "memory");
        __builtin_amdgcn_s_barrier();
    }

    // wave 3 holds energies (outputs 60..66 = acc[9..15]); softmax over k per px
    if (wv == 3) {
        float4 a[K_];
#pragma unroll
        for (int k = 0; k < K_; k++) {
            float e = ebias[n * K_ + k];
            a[k] = make_float4(acc[9+k].x + e, acc[9+k].y + e,
                               acc[9+k].z + e, acc[9+k].w + e);
        }
        float4 mm = a[0];
#pragma unroll
        for (int k = 1; k < K_; k++) mm = f4max(mm, a[k]);
        float4 sum = make_float4(0.f, 0.f, 0.f, 0.f);
#pragma unroll
        for (int k = 0; k < K_; k++) {
            a[k] = make_float4(__expf(a[k].x - mm.x), __expf(a[k].y - mm.y),
                               __expf(a[k].z - mm.z), __expf(a[k].w - mm.w));
            sum.x += a[k].x; sum.y += a[k].y; sum.z += a[k].z; sum.w += a[k].w;
        }
        float4 inv = make_float4(1.f/sum.x, 1.f/sum.y, 1.f/sum.z, 1.f/sum.w);
#pragma unroll
        for (int k = 0; k < K_; k++)
            ((float4*)&a_lds[k][0])[lane] =
                make_float4(a[k].x*inv.x, a[k].y*inv.y, a[k].z*inv.z, a[k].w*inv.w);
    }
    __syncthreads();

    float4 a4[K_];
#pragma unroll
    for (int k = 0; k < K_; k++) a4[k] = ((const float4*)&a_lds[k][0])[lane];
    int nout = (wv == 3) ? 9 : 17;
    int ob = wv * 17;
#pragma unroll
    for (int i = 0; i < 17; i++) {
        if (i < nout) {
            int o = ob + i;
            float4 s = make_float4(0.f, 0.f, 0.f, 0.f);
#pragma unroll
            for (int k = 0; k < K_; k++) {
                float mv = sm2[o * K_ + k];
                s.x += mv * a4[k].x; s.y += mv * a4[k].y;
                s.z += mv * a4[k].z; s.w += mv * a4[k].w;
            }
            acc[i].x += s.x; acc[i].y += s.y; acc[i].z += s.z; acc[i].w += s.w;
        }
    }

    // store pre-BN y + per-block BN partials
    float* yp = y + (size_t)n * OUTC_ * S_ + tile * 256 + lane * 4;
#pragma unroll
    for (int i = 0; i < 17; i++) {
        if (i < nout) {
            int o = ob + i;
            *(float4*)(yp + (size_t)o * S_) = acc[i];
            float sm = acc[i].x + acc[i].y + acc[i].z + acc[i].w;
            float sq = acc[i].x*acc[i].x + acc[i].y*acc[i].y +
                       acc[i].z*acc[i].z + acc[i].w*acc[i].w;
            for (int off = 32; off; off >>= 1) {
                sm += __shfl_xor(sm, off, 64);
                sq += __shfl_xor(sq, off, 64);
            }
            if (lane == 0) { tot[o] = sm; tot[60 + o] = sq; }
        }
    }
    __syncthreads();
    if (tid < 120) part[(size_t)blockIdx.x * 120 + tid] = tot[tid];
}

// ---------------- kernel D: BN statistics ----------------
__global__ void k_bn(const float* __restrict__ part, const float* __restrict__ gamma,
                     const float* __restrict__ beta, float* __restrict__ scl,
                     float* __restrict__ shf) {
    int t = threadIdx.x & 127, q = threadIdx.x >> 7;   // 512 threads
    __shared__ float red[4][120];
    __shared__ float tot[120];
    if (t < 120) {
        float s = 0.f;
        for (int b = q * 128; b < q * 128 + 128; b++) s += part[(size_t)b * 120 + t];
        red[q][t] = s;
    }
    __syncthreads();
    if (threadIdx.x < 120)
        tot[threadIdx.x] = red[0][threadIdx.x] + red[1][threadIdx.x] +
                           red[2][threadIdx.x] + red[3][threadIdx.x];
    __syncthreads();
    if (threadIdx.x < OUTC_) {
        const float invn = 1.f / (float)(N_ * S_);
        float mean = tot[threadIdx.x] * invn;
        float var = tot[60 + threadIdx.x] * invn - mean * mean;
        float sc = gamma[threadIdx.x] * rsqrtf(var + BN_EPS);
        scl[threadIdx.x] = sc;
        shf[threadIdx.x] = beta[threadIdx.x] - mean * sc;
    }
}

// ---------------- kernel E: in-place BN apply + ReLU ----------------
__global__ void k_apply(float* __restrict__ y, const float* __restrict__ scl,
                        const float* __restrict__ shf) {
    int idx = blockIdx.x * 256 + threadIdx.x;          // float4 index
    int o = (idx >> 12) % OUTC_;
    float4 v = ((const float4*)y)[idx];
    float a = scl[o], b = shf[o];
    v.x = fmaxf(v.x * a + b, 0.f);
    v.y = fmaxf(v.y * a + b, 0.f);
    v.z = fmaxf(v.z * a + b, 0.f);
    v.w = fmaxf(v.w * a + b, 0.f);
    ((float4*)y)[idx] = v;
}

extern "C" void kernel_launch(void* const* d_in, const int* in_sizes, int n_in,
                              void* d_out, int out_size, void* d_ws, size_t ws_size,
                              hipStream_t stream) {
    const float* p_fea = (const float*)d_in[0];
    const float* p_seg = (const float*)d_in[1];
    const float* Wq    = (const float*)d_in[2];
    const float* bq    = (const float*)d_in[3];
    const float* Wk    = (const float*)d_in[4];
    const float* bk    = (const float*)d_in[5];
    const float* Wp    = (const float*)d_in[6];
    const float* gamma = (const float*)d_in[7];
    const float* beta  = (const float*)d_in[8];

    float* ws    = (float*)d_ws;
    float* num   = ws + OFF_NUM;
    float* den   = ws + OFF_DEN;
    float* eb    = ws + OFF_EB;
    float* m2    = ws + OFF_M2;
    float* wpt80 = ws + OFF_WPT80;
    float* part  = ws + OFF_PART;
    float* scl   = ws + OFF_SCL;
    float* shf   = ws + OFF_SHF;
    float* ybuf  = (float*)d_out;

    hipMemsetAsync(num, 0, 14400 * sizeof(float), stream);   // num + den
    k_pool<<<512, 256, 0, stream>>>(p_fea, p_seg, num, den);
    k_center<<<8, 256, 0, stream>>>(num, den, Wq, bq, Wk, bk, Wp, eb, m2, wpt80);
    k_main<<<512, 256, 0, stream>>>(p_fea, wpt80, eb, m2, ybuf, part);
    k_bn<<<1, 512, 0, stream>>>(part, gamma, beta, scl, shf);
    k_apply<<<(N_ * OUTC_ * S_ / 4) / 256, 256, 0, stream>>>(ybuf, scl, shf);
}

// Round 5
// 199.688 us; speedup vs baseline: 2.3567x; 1.0132x over previous
//
#include <hip/hip_runtime.h>

#define N_    8
#define C_    256
#define K_    7
#define HID_  10
#define OUTC_ 60
#define S_    16384
#define BN_EPS 1e-5f

// ---- workspace layout (float offsets, all 16B-aligned) ----
#define OFF_PP     0        // pool partials: [n][sh][oct][64] = 8*2*32*64 = 32768
#define OFF_DP     32768    // den partials:  [n][sh][8] = 128
#define OFF_EB     32896    // 64
#define OFF_M2     32960    // 3392
#define OFF_WPT80  36352    // N*256*80 = 163840 (col 20w+j = output 17w+j, j<17)
#define OFF_PART   200192   // 512*120 = 61440
#define OFF_SCL    261632   // 64
#define OFF_SHF    261696   // 64
// total 261760 floats ~= 1.05 MB

#define GLDS(g, l) __builtin_amdgcn_global_load_lds( \
    (const __attribute__((address_space(1))) unsigned int*)(g), \
    (__attribute__((address_space(3))) unsigned int*)(l), 16, 0, 0)

__device__ __forceinline__ float4 f4max(float4 a, float4 b) {
    return make_float4(fmaxf(a.x,b.x), fmaxf(a.y,b.y), fmaxf(a.z,b.z), fmaxf(a.w,b.w));
}

// ---------------- kernel A: fused class-softmax + pooling GEMM ----------------
// 512 blocks xcd-chunked: XCD x owns n=x; NO atomics - per-block partials
__global__ void __launch_bounds__(256) k_pool(
        const float* __restrict__ fea, const float* __restrict__ seg,
        float* __restrict__ pp, float* __restrict__ dp) {
    int b = blockIdx.x;
    int lin = (b & 7) * 64 + (b >> 3);
    int n = lin >> 6, r = lin & 63;
    int oct = r >> 1, c0 = oct * 8, sh = r & 1;
    int tid = threadIdx.x;
    const float* sp = seg + (size_t)n * K_ * S_ + sh * 8192 + tid * 4;
    const float* fp = fea + ((size_t)n * C_ + c0) * S_ + sh * 8192 + tid * 4;

    float acc[8][K_] = {};
    float dsum[K_] = {};
#pragma unroll 2
    for (int it = 0; it < 8; it++) {
        int s = it * 1024;
        float4 sv[K_], fv[8];
#pragma unroll
        for (int k = 0; k < K_; k++) sv[k] = *(const float4*)(sp + (size_t)k * S_ + s);
#pragma unroll
        for (int c = 0; c < 8; c++) fv[c] = *(const float4*)(fp + (size_t)c * S_ + s);
        float4 m = sv[0];
#pragma unroll
        for (int k = 1; k < K_; k++) m = f4max(m, sv[k]);
        float4 sum = make_float4(0.f, 0.f, 0.f, 0.f);
        float4 a[K_];
#pragma unroll
        for (int k = 0; k < K_; k++) {
            a[k] = make_float4(__expf(sv[k].x - m.x), __expf(sv[k].y - m.y),
                               __expf(sv[k].z - m.z), __expf(sv[k].w - m.w));
            sum.x += a[k].x; sum.y += a[k].y; sum.z += a[k].z; sum.w += a[k].w;
        }
        float4 inv = make_float4(1.f/sum.x, 1.f/sum.y, 1.f/sum.z, 1.f/sum.w);
#pragma unroll
        for (int k = 0; k < K_; k++) {
            a[k] = make_float4(a[k].x*inv.x, a[k].y*inv.y, a[k].z*inv.z, a[k].w*inv.w);
            dsum[k] += a[k].x + a[k].y + a[k].z + a[k].w;
        }
#pragma unroll
        for (int c = 0; c < 8; c++)
#pragma unroll
            for (int k = 0; k < K_; k++)
                acc[c][k] += fv[c].x*a[k].x + fv[c].y*a[k].y + fv[c].z*a[k].z + fv[c].w*a[k].w;
    }
    __shared__ float red[4][63];
    int lane = tid & 63, wv = tid >> 6;
#pragma unroll
    for (int i = 0; i < 56; i++) {
        float v = acc[i / K_][i % K_];
        for (int off = 32; off; off >>= 1) v += __shfl_xor(v, off, 64);
        if (lane == 0) red[wv][i] = v;
    }
    if (oct == 0) {
#pragma unroll
        for (int k = 0; k < K_; k++) {
            float v = dsum[k];
            for (int off = 32; off; off >>= 1) v += __shfl_xor(v, off, 64);
            if (lane == 0) red[wv][56 + k] = v;
        }
    }
    __syncthreads();
    if (tid < 56) {
        float v = red[0][tid] + red[1][tid] + red[2][tid] + red[3][tid];
        pp[(((size_t)n * 2 + sh) * 32 + oct) * 64 + tid] = v;
    } else if (tid >= 56 && tid < 63 && oct == 0) {
        float v = red[0][tid] + red[1][tid] + red[2][tid] + red[3][tid];
        dp[((size_t)n * 2 + sh) * 8 + (tid - 56)] = v;
    }
}

// ---------------- kernel B: reduce partials -> p_center -> wpt80, ebias, M2 ----
__global__ void k_center(const float* __restrict__ pp, const float* __restrict__ dp,
                         const float* __restrict__ Wq, const float* __restrict__ bq,
                         const float* __restrict__ Wk, const float* __restrict__ bk,
                         const float* __restrict__ Wp,
                         float* __restrict__ eb, float* __restrict__ m2,
                         float* __restrict__ wpt80) {
    int n = blockIdx.x, tid = threadIdx.x;
    __shared__ float pc[C_ * K_];     // [c][k]
    __shared__ float ql[HID_ * K_];   // [o][k]
    __shared__ float dinv[K_];
    if (tid < K_) {
        float d = dp[((size_t)n * 2 + 0) * 8 + tid] + dp[((size_t)n * 2 + 1) * 8 + tid];
        dinv[tid] = 1.f / d;
    }
    __syncthreads();
    for (int i = tid; i < C_ * K_; i += 256) {
        int c = i / K_, k = i - c * K_;
        int oct = c >> 3, ci = c & 7;
        float v = pp[(((size_t)n * 2 + 0) * 32 + oct) * 64 + ci * K_ + k]
                + pp[(((size_t)n * 2 + 1) * 32 + oct) * 64 + ci * K_ + k];
        pc[i] = v * dinv[k];
    }
    __syncthreads();
    if (tid < HID_ * K_) {
        int o = tid / K_, k = tid % K_;
        float s = bq[o];
        for (int c = 0; c < C_; c++) s += Wq[o * C_ + c] * pc[c * K_ + k];
        ql[tid] = s;
    }
    __syncthreads();
    // wpt80[c][80]: col 20w+j (j<17) = output o=17w+j; o<60 -> Wp1^T, 60..66 -> Wqk
    for (int i = tid; i < C_ * 80; i += 256) {
        int c = i / 80, cc = i % 80;
        int w = cc / 20, j = cc % 20;
        float v = 0.f;
        if (j < 17) {
            int o = 17 * w + j;
            if (o < 60) v = Wp[o * 2 * C_ + c];
            else if (o < 67) {
                int k = o - 60;
                for (int o2 = 0; o2 < HID_; o2++) v += ql[o2 * K_ + k] * Wk[o2 * C_ + c];
            }
        }
        wpt80[(size_t)n * C_ * 80 + i] = v;
    }
    if (tid < K_) {
        float s = 0.f;
        for (int o = 0; o < HID_; o++) s += ql[o * K_ + tid] * bk[o];
        eb[n * K_ + tid] = s;
    }
    for (int i = tid; i < OUTC_ * K_; i += 256) {
        int o = i / K_, k = i % K_;
        float s = 0.f;
        for (int c = 0; c < C_; c++) s += Wp[o * 2 * C_ + C_ + c] * pc[c * K_ + k];
        m2[(size_t)n * OUTC_ * K_ + i] = s;
    }
}

// ---------------- kernel C: fused energy/softmax/projection ----------------
// 512 blocks xcd-chunked; wave w owns outputs 17w..17w+16; thread owns 4 px
__global__ void __launch_bounds__(256, 2) k_main(
        const float* __restrict__ fea, const float* __restrict__ wpt80,
        const float* __restrict__ ebias, const float* __restrict__ m2,
        float* __restrict__ y, float* __restrict__ part) {
    int g = blockIdx.x;
    int lin = (g & 7) * 64 + (g >> 3);
    int n = lin >> 6, tile = lin & 63;
    int tid = threadIdx.x, lane = tid & 63, wv = tid >> 6;

    __shared__ __align__(16) float sw[2][5120];      // 2 x 20KB weight chunks
    __shared__ __align__(16) float sm2[424];
    __shared__ __align__(16) float a_lds[K_][256];
    __shared__ float tot[120];

    for (int i = tid; i < OUTC_ * K_; i += 256)
        sm2[i] = m2[(size_t)n * OUTC_ * K_ + i];

    const float* wsrc = wpt80 + (size_t)n * (C_ * 80);
    const float* fp = fea + (size_t)n * C_ * S_ + tile * 256 + lane * 4;

    float4 acc[17];
#pragma unroll
    for (int i = 0; i < 17; i++) acc[i] = make_float4(0.f, 0.f, 0.f, 0.f);

    {   // stage chunk 0
#pragma unroll
        for (int i = 0; i < 5; i++) {
            int fi = i * 1024 + wv * 256;            // wave-uniform lds base
            GLDS(wsrc + fi + lane * 4, &sw[0][fi]);
        }
    }
    // 4-deep fea channel prefetch
    float4 fbuf[4];
#pragma unroll
    for (int j = 0; j < 4; j++) fbuf[j] = *(const float4*)(fp + (size_t)j * S_);

    asm volatile("s_waitcnt vmcnt(0) lgkmcnt(0)" ::: "memory");
    __builtin_amdgcn_s_barrier();

    const int wb = 20 * wv;
    for (int ch = 0; ch < 4; ch++) {
        int bb = ch & 1;
        if (ch < 3) {
            const float* s1 = wsrc + (ch + 1) * 5120;
#pragma unroll
            for (int i = 0; i < 5; i++) {
                int fi = i * 1024 + wv * 256;
                GLDS(s1 + fi + lane * 4, &sw[bb ^ 1][fi]);
            }
        }
#pragma unroll 4
        for (int cc = 0; cc < 64; cc++) {
            int cg = ch * 64 + cc;
            float4 f = fbuf[cg & 3];
            fbuf[cg & 3] = *(const float4*)(fp + (size_t)((cg + 4) & 255) * S_);
            const float* wr = &sw[bb][cc * 80 + wb];         // wave-uniform -> broadcast
            float4 w0 = *(const float4*)wr;
            float4 w1 = *(const float4*)(wr + 4);
            float4 w2 = *(const float4*)(wr + 8);
            float4 w3 = *(const float4*)(wr + 12);
            float wx = wr[16];
#define FMA4(j, ww) acc[j].x += (ww) * f.x; acc[j].y += (ww) * f.y; \
                    acc[j].z += (ww) * f.z; acc[j].w += (ww) * f.w;
            FMA4(0, w0.x) FMA4(1, w0.y) FMA4(2, w0.z) FMA4(3, w0.w)
            FMA4(4, w1.x) FMA4(5, w1.y) FMA4(6, w1.z) FMA4(7, w1.w)
            FMA4(8, w2.x) FMA4(9, w2.y) FMA4(10, w2.z) FMA4(11, w2.w)
            FMA4(12, w3.x) FMA4(13, w3.y) FMA4(14, w3.z) FMA4(15, w3.w)
            FMA4(16, wx)
#undef FMA4
        }
        asm volatile("s_waitcnt vmcnt(0)" ::: "memory");
        __builtin_amdgcn_s_barrier();
    }

    // wave 3 holds energies (outputs 60..66 = acc[9..15]); softmax over k per px
    if (wv == 3) {
        float4 a[K_];
#pragma unroll
        for (int k = 0; k < K_; k++) {
            float e = ebias[n * K_ + k];
            a[k] = make_float4(acc[9+k].x + e, acc[9+k].y + e,
                               acc[9+k].z + e, acc[9+k].w + e);
        }
        float4 mm = a[0];
#pragma unroll
        for (int k = 1; k < K_; k++) mm = f4max(mm, a[k]);
        float4 sum = make_float4(0.f, 0.f, 0.f, 0.f);
#pragma unroll
        for (int k = 0; k < K_; k++) {
            a[k] = make_float4(__expf(a[k].x - mm.x), __expf(a[k].y - mm.y),
                               __expf(a[k].z - mm.z), __expf(a[k].w - mm.w));
            sum.x += a[k].x; sum.y += a[k].y; sum.z += a[k].z; sum.w += a[k].w;
        }
        float4 inv = make_float4(1.f/sum.x, 1.f/sum.y, 1.f/sum.z, 1.f/sum.w);
#pragma unroll
        for (int k = 0; k < K_; k++)
            ((float4*)&a_lds[k][0])[lane] =
                make_float4(a[k].x*inv.x, a[k].y*inv.y, a[k].z*inv.z, a[k].w*inv.w);
    }
    __syncthreads();

    float4 a4[K_];
#pragma unroll
    for (int k = 0; k < K_; k++) a4[k] = ((const float4*)&a_lds[k][0])[lane];
    int nout = (wv == 3) ? 9 : 17;
    int ob = wv * 17;
#pragma unroll
    for (int i = 0; i < 17; i++) {
        if (i < nout) {
            int o = ob + i;
            float4 s = make_float4(0.f, 0.f, 0.f, 0.f);
#pragma unroll
            for (int k = 0; k < K_; k++) {
                float mv = sm2[o * K_ + k];
                s.x += mv * a4[k].x; s.y += mv * a4[k].y;
                s.z += mv * a4[k].z; s.w += mv * a4[k].w;
            }
            acc[i].x += s.x; acc[i].y += s.y; acc[i].z += s.z; acc[i].w += s.w;
        }
    }

    // store pre-BN y + per-block BN partials
    float* yp = y + (size_t)n * OUTC_ * S_ + tile * 256 + lane * 4;
#pragma unroll
    for (int i = 0; i < 17; i++) {
        if (i < nout) {
            int o = ob + i;
            *(float4*)(yp + (size_t)o * S_) = acc[i];
            float sm = acc[i].x + acc[i].y + acc[i].z + acc[i].w;
            float sq = acc[i].x*acc[i].x + acc[i].y*acc[i].y +
                       acc[i].z*acc[i].z + acc[i].w*acc[i].w;
            for (int off = 32; off; off >>= 1) {
                sm += __shfl_xor(sm, off, 64);
                sq += __shfl_xor(sq, off, 64);
            }
            if (lane == 0) { tot[o] = sm; tot[60 + o] = sq; }
        }
    }
    __syncthreads();
    if (tid < 120) part[(size_t)blockIdx.x * 120 + tid] = tot[tid];
}

// ---------------- kernel D: BN statistics ----------------
__global__ void k_bn(const float* __restrict__ part, const float* __restrict__ gamma,
                     const float* __restrict__ beta, float* __restrict__ scl,
                     float* __restrict__ shf) {
    int t = threadIdx.x & 127, q = threadIdx.x >> 7;   // 512 threads
    __shared__ float red[4][120];
    __shared__ float tot[120];
    if (t < 120) {
        float s = 0.f;
        for (int b = q * 128; b < q * 128 + 128; b++) s += part[(size_t)b * 120 + t];
        red[q][t] = s;
    }
    __syncthreads();
    if (threadIdx.x < 120)
        tot[threadIdx.x] = red[0][threadIdx.x] + red[1][threadIdx.x] +
                           red[2][threadIdx.x] + red[3][threadIdx.x];
    __syncthreads();
    if (threadIdx.x < OUTC_) {
        const float invn = 1.f / (float)(N_ * S_);
        float mean = tot[threadIdx.x] * invn;
        float var = tot[60 + threadIdx.x] * invn - mean * mean;
        float sc = gamma[threadIdx.x] * rsqrtf(var + BN_EPS);
        scl[threadIdx.x] = sc;
        shf[threadIdx.x] = beta[threadIdx.x] - mean * sc;
    }
}

// ---------------- kernel E: in-place BN apply + ReLU ----------------
__global__ void k_apply(float* __restrict__ y, const float* __restrict__ scl,
                        const float* __restrict__ shf) {
    int idx = blockIdx.x * 256 + threadIdx.x;          // float4 index
    int o = (idx >> 12) % OUTC_;
    float4 v = ((const float4*)y)[idx];
    float a = scl[o], b = shf[o];
    v.x = fmaxf(v.x * a + b, 0.f);
    v.y = fmaxf(v.y * a + b, 0.f);
    v.z = fmaxf(v.z * a + b, 0.f);
    v.w = fmaxf(v.w * a + b, 0.f);
    ((float4*)y)[idx] = v;
}

extern "C" void kernel_launch(void* const* d_in, const int* in_sizes, int n_in,
                              void* d_out, int out_size, void* d_ws, size_t ws_size,
                              hipStream_t stream) {
    const float* p_fea = (const float*)d_in[0];
    const float* p_seg = (const float*)d_in[1];
    const float* Wq    = (const float*)d_in[2];
    const float* bq    = (const float*)d_in[3];
    const float* Wk    = (const float*)d_in[4];
    const float* bk    = (const float*)d_in[5];
    const float* Wp    = (const float*)d_in[6];
    const float* gamma = (const float*)d_in[7];
    const float* beta  = (const float*)d_in[8];

    float* ws    = (float*)d_ws;
    float* pp    = ws + OFF_PP;
    float* dp    = ws + OFF_DP;
    float* eb    = ws + OFF_EB;
    float* m2    = ws + OFF_M2;
    float* wpt80 = ws + OFF_WPT80;
    float* part  = ws + OFF_PART;
    float* scl   = ws + OFF_SCL;
    float* shf   = ws + OFF_SHF;
    float* ybuf  = (float*)d_out;

    k_pool<<<512, 256, 0, stream>>>(p_fea, p_seg, pp, dp);
    k_center<<<8, 256, 0, stream>>>(pp, dp, Wq, bq, Wk, bk, Wp, eb, m2, wpt80);
    k_main<<<512, 256, 0, stream>>>(p_fea, wpt80, eb, m2, ybuf, part);
    k_bn<<<1, 512, 0, stream>>>(part, gamma, beta, scl, shf);
    k_apply<<<(N_ * OUTC_ * S_ / 4) / 256, 256, 0, stream>>>(ybuf, scl, shf);
}